// Round 6
// baseline (119.276 us; speedup 1.0000x reference)
//
#include <hip/hip_runtime.h>

// out: 4 tensors (32, 20, 14, 14, 14, 14) fp32 concatenated.
// Block = (n, q, d2); 4 waves, wave w owns output tensor w (linear store stream).
//   out_p(i,j)[d3][ps] = F_i[d3][ps] * G_j[d3][ps]
//   F_i = A_i[d3,d4] * B_i[d3,d5]
//     A_i[d3,d4] = 0.5*cor_i[0,pc]*cor_i[1+q,pc]*cor_i[23+d4,pc],  pc=d2*14+d3
//     B_i[d3,d5] = cor_i[37+d5,pc]
//   G_j = T_j[ps] * cen_j[37+d3,ps]
//     T_j[ps] = cen_j[0,ps]*cen_j[1+q,ps]*cen_j[23+d2,ps]
// wave0=p1=(i1,j1) wave1=p2=(i2,j1) wave2=p3=(i1,j2) wave3=p4=(i2,j2)

#define S_PER 24586240u            // 32*20*14^4 elements per tensor
#define TSTRIDE (51 * 196)
#define N_STRIDE (204 * 196)

__global__ __launch_bounds__(256) void plnet_kernel(const float* __restrict__ in,
                                                    float* __restrict__ out) {
    __shared__ __align__(16) float sT1[196];
    __shared__ __align__(16) float sT2[196];
    __shared__ float sA1[196], sA2[196];   // [d3*14 + d4]
    __shared__ float sB1[196], sB2[196];   // [d3*14 + d5]

    const unsigned b  = blockIdx.x;        // = (n*20 + q)*14 + d2
    const unsigned d2 = b % 14u;
    const unsigned nq = b / 14u;
    const unsigned q  = nq % 20u;
    const unsigned n  = nq / 20u;

    const float* g    = in + (size_t)n * N_STRIDE;
    const float* cor1 = g;
    const float* cor2 = g + TSTRIDE;
    const float* cen1 = g + 2 * TSTRIDE;
    const float* cen2 = g + 3 * TSTRIDE;

    const unsigned tid = threadIdx.x;

    // ---- Prologue: 6 small LDS tables, one barrier (identical to R3) ----
    if (tid < 196u) {
        const unsigned ps = tid;
        sT1[ps] = cen1[ps] * cen1[(1u + q) * 196u + ps] * cen1[(23u + d2) * 196u + ps];
        sT2[ps] = cen2[ps] * cen2[(1u + q) * 196u + ps] * cen2[(23u + d2) * 196u + ps];
        const unsigned d3 = ps / 14u;
        const unsigned k  = ps - d3 * 14u;
        const unsigned pc = d2 * 14u + d3;
        const float k1 = 0.5f * cor1[pc] * cor1[(1u + q) * 196u + pc];
        const float k2 = 0.5f * cor2[pc] * cor2[(1u + q) * 196u + pc];
        sA1[ps] = k1 * cor1[(23u + k) * 196u + pc];
        sA2[ps] = k2 * cor2[(23u + k) * 196u + pc];
        sB1[ps] = cor1[(37u + k) * 196u + pc];
        sB2[ps] = cor2[(37u + k) * 196u + pc];
    }
    __syncthreads();

    // ---- Wave specialization: wave w -> tensor w ----
    const unsigned w    = tid >> 6;        // 0..3
    const unsigned lane = tid & 63u;
    const unsigned i    = w & 1u;          // corner index (0->cor1, 1->cor2)
    const unsigned j    = w >> 1;          // center index (0->cen1, 1->cen2)

    const float* At = i ? sA2 : sA1;       // LDS
    const float* Bt = i ? sB2 : sB1;
    const float* Tt = j ? sT2 : sT1;
    const float* vb = (j ? cen2 : cen1) + 37u * 196u;   // v rows base

    const size_t chunk = ((size_t)(n * 20u + q) * 196u + d2 * 14u) * 196u;
    float4* o = (float4*)(out + (size_t)w * S_PER + chunk);   // linear stream

    for (unsigned c = lane; c < 686u; c += 64u) {
        const unsigned d3 = c / 49u;
        const unsigned f  = c - d3 * 49u;
        const unsigned e  = 4u * f;          // ps of first element

        const float4 v = *(const float4*)&vb[d3 * 196u + e];
        const float4 t = *(const float4*)&Tt[e];
        const float4 G = make_float4(t.x * v.x, t.y * v.y, t.z * v.z, t.w * v.w);

        unsigned d4 = e / 14u;
        unsigned d5 = e - d4 * 14u;
        float F[4];
#pragma unroll
        for (int l = 0; l < 4; ++l) {
            F[l] = At[d3 * 14u + d4] * Bt[d3 * 14u + d5];
            ++d5;
            const unsigned carry = (d5 == 14u);
            d4 += carry;
            d5 = carry ? 0u : d5;
        }

        o[c] = make_float4(F[0] * G.x, F[1] * G.y, F[2] * G.z, F[3] * G.w);
    }
}

extern "C" void kernel_launch(void* const* d_in, const int* in_sizes, int n_in,
                              void* d_out, int out_size, void* d_ws, size_t ws_size,
                              hipStream_t stream) {
    const float* in = (const float*)d_in[0];
    float* out = (float*)d_out;
    dim3 grid(32 * 20 * 14);       // one block per (n, q, d2)
    dim3 block(256);
    plnet_kernel<<<grid, block, 0, stream>>>(in, out);
}

// Round 7
// 87.438 us; speedup vs baseline: 1.3641x; 1.3641x over previous
//
#include <hip/hip_runtime.h>

// out: 4 tensors (32, 20, 14, 14, 14, 14) fp32 concatenated.
// Block = (n, q, d2); each block writes 4 contiguous chunks of 14*196 floats.
// R6 = R3 + bijective XCD-contiguous block remap (write page-locality).
//   out_p[d3][ps] = F_i[d3][ps] * G_j[d3][ps]
//   F_i[d3][ps]   = A_i[d3][d4] * B_i[d3][d5]          (corner side)
//   A_i[d3][d4]   = 0.5*cor_i[0,pc]*cor_i[1+q,pc]*cor_i[23+d4,pc],  pc=d2*14+d3
//   B_i[d3][d5]   = cor_i[37+d5,pc]
//   G_j[d3][ps]   = T_j[ps] * cen_j[37+d3,ps]          (center side)
//   T_j[ps]       = cen_j[0,ps]*cen_j[1+q,ps]*cen_j[23+d2,ps]
// p1=F1*G1  p2=F2*G1  p3=F1*G2  p4=F2*G2

#define S_PER 24586240u            // 32*20*14^4 elements per tensor
#define TSTRIDE (51 * 196)
#define N_STRIDE (204 * 196)
#define NBLK 8960u                 // 32*20*14
#define NXCD 8u
#define BLK_PER_XCD (NBLK / NXCD)  // 1120

__global__ __launch_bounds__(256) void plnet_kernel(const float* __restrict__ in,
                                                    float* __restrict__ out) {
    __shared__ __align__(16) float sT1[196];
    __shared__ __align__(16) float sT2[196];
    __shared__ float sA1[196], sA2[196];   // [d3*14 + d4]
    __shared__ float sB1[196], sB2[196];   // [d3*14 + d5]

    // XCD-contiguous remap: hardware round-robins blockIdx across 8 XCDs;
    // give XCD x the contiguous output range [x*1120, (x+1)*1120).
    const unsigned raw = blockIdx.x;
    const unsigned b   = (raw % NXCD) * BLK_PER_XCD + raw / NXCD;

    const unsigned d2 = b % 14u;
    const unsigned nq = b / 14u;
    const unsigned q  = nq % 20u;
    const unsigned n  = nq / 20u;

    const float* g    = in + (size_t)n * N_STRIDE;
    const float* cor1 = g;
    const float* cor2 = g + TSTRIDE;
    const float* cen1 = g + 2 * TSTRIDE;
    const float* cen2 = g + 3 * TSTRIDE;

    const unsigned tid = threadIdx.x;

    // ---- Prologue: 6 small LDS tables, one barrier ----
    if (tid < 196u) {
        const unsigned ps = tid;
        sT1[ps] = cen1[ps] * cen1[(1u + q) * 196u + ps] * cen1[(23u + d2) * 196u + ps];
        sT2[ps] = cen2[ps] * cen2[(1u + q) * 196u + ps] * cen2[(23u + d2) * 196u + ps];
        const unsigned d3 = ps / 14u;
        const unsigned k  = ps - d3 * 14u;
        const unsigned pc = d2 * 14u + d3;
        const float k1 = 0.5f * cor1[pc] * cor1[(1u + q) * 196u + pc];
        const float k2 = 0.5f * cor2[pc] * cor2[(1u + q) * 196u + pc];
        sA1[ps] = k1 * cor1[(23u + k) * 196u + pc];
        sA2[ps] = k2 * cor2[(23u + k) * 196u + pc];
        sB1[ps] = cor1[(37u + k) * 196u + pc];
        sB2[ps] = cor2[(37u + k) * 196u + pc];
    }
    __syncthreads();

    // ---- Main: 686 float4-items over (d3, ps/4); contiguous stores ----
    const size_t chunk = ((size_t)(n * 20u + q) * 196u + d2 * 14u) * 196u;
    float4* o1 = (float4*)(out + chunk);
    float4* o2 = (float4*)(out + (size_t)S_PER + chunk);
    float4* o3 = (float4*)(out + 2u * (size_t)S_PER + chunk);
    float4* o4 = (float4*)(out + 3u * (size_t)S_PER + chunk);

    for (unsigned c = tid; c < 686u; c += 256u) {
        const unsigned d3 = c / 49u;
        const unsigned f  = c - d3 * 49u;
        const unsigned e  = 4u * f;          // ps of first element

        const float4 t1 = *(const float4*)&sT1[e];
        const float4 t2 = *(const float4*)&sT2[e];
        const float4 v1 = *(const float4*)&cen1[(37u + d3) * 196u + e];
        const float4 v2 = *(const float4*)&cen2[(37u + d3) * 196u + e];

        const float4 G1 = make_float4(t1.x * v1.x, t1.y * v1.y, t1.z * v1.z, t1.w * v1.w);
        const float4 G2 = make_float4(t2.x * v2.x, t2.y * v2.y, t2.z * v2.z, t2.w * v2.w);

        // per-element corner factors
        unsigned d4 = e / 14u;
        unsigned d5 = e - d4 * 14u;
        float F1[4], F2[4];
#pragma unroll
        for (int l = 0; l < 4; ++l) {
            F1[l] = sA1[d3 * 14u + d4] * sB1[d3 * 14u + d5];
            F2[l] = sA2[d3 * 14u + d4] * sB2[d3 * 14u + d5];
            ++d5;
            const unsigned carry = (d5 == 14u);
            d4 += carry;
            d5 = carry ? 0u : d5;
        }

        o1[c] = make_float4(F1[0] * G1.x, F1[1] * G1.y, F1[2] * G1.z, F1[3] * G1.w);
        o2[c] = make_float4(F2[0] * G1.x, F2[1] * G1.y, F2[2] * G1.z, F2[3] * G1.w);
        o3[c] = make_float4(F1[0] * G2.x, F1[1] * G2.y, F1[2] * G2.z, F1[3] * G2.w);
        o4[c] = make_float4(F2[0] * G2.x, F2[1] * G2.y, F2[2] * G2.z, F2[3] * G2.w);
    }
}

extern "C" void kernel_launch(void* const* d_in, const int* in_sizes, int n_in,
                              void* d_out, int out_size, void* d_ws, size_t ws_size,
                              hipStream_t stream) {
    const float* in = (const float*)d_in[0];
    float* out = (float*)d_out;
    dim3 grid(NBLK);               // one block per (n, q, d2), XCD-remapped inside
    dim3 block(256);
    plnet_kernel<<<grid, block, 0, stream>>>(in, out);
}